// Round 9
// baseline (1257.239 us; speedup 1.0000x reference)
//
#include <hip/hip_runtime.h>
#include <stdint.h>

// LSTM B=256,T=512,F=32,U=350; gates i,f,g(relu),o; h=o*relu(c); out=h.dw+db
//
// R16: R14 base (929us) + LDS-shared h slab between the block's 2 waves.
//  R15 postmortem: halving per-wave MFMA changed absolute MFMA time 0% ->
//  MFMA on the critical path is ~300cy (per-CU shared pipe ~4.9cy/MFMA),
//  not ~930; split-K only added coupling. Reverted.
//  Dominant residual (R10 evidence: consumer L2 path services ~3 line-
//  req/cy/XCD): each step 44 waves/XCD re-fetch the SAME 11KB slab =
//  7.8k line-requests ~ 2.6kcy of L2 service inside every step.
//  Change: the 2 waves of a block split the load: wave0 spins tags 0..11,
//  loads blocks 0..5; wave1 tags 12..21, blocks 6..10. Each ds_writes its
//  half into lds_stage[t&1][blk][lane][16B] (conflict-free), raw s_barrier
//  (lgkmcnt drain only, NO vmcnt), both ds_read all 11 blocks -> MFMA.
//  XCD requests/step halve. No new lockstep: both waves' spins already end
//  at the same last-tag instant. Stage race depth-2-safe: ds_write at t+2
//  postdates barrier_{t+1} which postdates partner's ds_reads at t.
//  Everything else byte-identical R14: bf16 A-frag fast slab, 22-word tag
//  array w/ RELEASE-workgroup publish, publish-before-dense, top-of-loop
//  x prefetch, distress->mirror degraded mode (per-wave subset), depth-2
//  ping-pong proof.

#define T_   512
#define F_   32
#define U_   350
#define G4   1400
#define NGRP 16
#define NB   16
#define NCB  11
#define KC   12
#define NT   88
#define HSLOTUS 5632    // ushorts per bf16 fast slot (11 blk * 512)
#define SLOTW   5632    // u32 words per mirror slot (R10 layout)

typedef __attribute__((ext_vector_type(8))) short  short8;
typedef __attribute__((ext_vector_type(4))) short  short4_;
typedef __attribute__((ext_vector_type(4))) float  float4_;
typedef unsigned long long u64t;

__device__ __forceinline__ short f2bf(float f) {
  union { float f; uint32_t u; } v; v.f = f;
  return (short)((v.u + 0x7FFFu + ((v.u >> 16) & 1u)) >> 16);
}

// ---- workspace layout (bytes) ----
#define SZ_W     (NT*KC*64*8*2u)                        // 1,081,344
#define OFF_XBF  (SZ_W)
#define SZ_XBF   (256u*T_*F_*2u)                        // 8,388,608
#define OFF_HBUF (OFF_XBF + SZ_XBF)
#define SZ_HBUF  (NGRP*2u*HSLOTUS*2u)                   // 360,448
#define OFF_HMIR (OFF_HBUF + SZ_HBUF)
#define SZ_HMIR  (NGRP*2u*SLOTW*4u)                     // 720,896
#define OFF_TAG  (OFF_HMIR + SZ_HMIR)
#define SZ_TAG   (NGRP*2u*32u*4u)                       // 4,096
#define OFF_FLG  (OFF_TAG + SZ_TAG)
#define SZ_FLG   (NGRP*16u*4u)                          // 1,024
#define OFF_WP   (OFF_FLG + SZ_FLG)
#define SZ_WP    (NGRP*NCB*NB*T_*4u)                    // 5,767,168

// ---- prep: W_swz[kc][tile][lane][8] bf16 in MFMA B-fragment order ----
__global__ void prep_w(const float* __restrict__ kern,
                       const float* __restrict__ rk,
                       const float* __restrict__ bias,
                       short* __restrict__ wswz) {
  const int tile = blockIdx.x, lane = threadIdx.x;
  const int g = tile / 22, jt = tile % 22;
  const int colg = jt * 16 + (lane & 15);
  const int src = g * U_ + colg;
  const bool valid = (colg < U_);
  const int kbase = (lane >> 4) * 8;
  for (int kc = 0; kc < KC; ++kc) {
    short8 pack;
    #pragma unroll
    for (int jj = 0; jj < 8; ++jj) {
      int k = kc * 32 + kbase + jj;
      float v = 0.f;
      if (valid) {
        if (k < F_)            v = kern[k * G4 + src];
        else if (k < F_ + U_)  v = rk[(k - F_) * G4 + src];
        else if (k == F_ + U_) v = bias[src];
      }
      pack[jj] = f2bf(v);
    }
    *(short8*)(wswz + (((size_t)kc * NT + tile) * 64 + lane) * 8) = pack;
  }
}

// ---- prep: x f32 -> bf16 ([b][t][f], contiguous 16B A-frag loads) ----
__global__ void prep_x(const float* __restrict__ x, short* __restrict__ xbf) {
  int i = (blockIdx.x * 256 + threadIdx.x) * 4;
  float4_ v = *(const float4_*)(x + i);
  short4_ o;
  #pragma unroll
  for (int jj = 0; jj < 4; ++jj) o[jj] = f2bf(v[jj]);
  *(short4_*)(xbf + i) = o;
}

// ---- init: slot1 = h_{-1}=0 tag 0 (bias col 350 = 1.0); tags; flag ----
// Fast slot0 / mirror slot0 need no init (reads are tag-gated / tag-in-word
// poison-safe). Tag slot0 init 0 is safe: slot0 wants odd tags only.
__global__ void init_all(unsigned short* __restrict__ hb16,
                         uint32_t* __restrict__ hmir32,
                         uint32_t* __restrict__ tagbuf,
                         uint32_t* __restrict__ flagbuf) {
  int i = blockIdx.x * 256 + threadIdx.x;            // 0 .. NGRP*5632-1
  int grp = i / HSLOTUS, rem = i % HSLOTUS;
  // fast bf16 slot1: rem = blk*512 + (quad_c*16+row)*8 + cpos
  {
    int blk = rem >> 9, quadc = (rem >> 7) & 3, cpos = rem & 7;
    int col = blk * 32 + quadc * 8 + cpos;
    hb16[(size_t)(grp * 2 + 1) * HSLOTUS + rem] =
        (col == 350) ? (unsigned short)0x3F80 : 0;
  }
  // mirror slot1 (R10 tag-in-word layout)
  {
    int blkm = rem >> 8, off = rem & 255;
    int fi = blkm >> 1, fk2 = blkm & 1, fquadc = off >> 6;
    int fk1 = (off >> 1) & 1, fb = off & 1;
    int fcol = fi * 32 + fquadc * 8 + fk2 * 4 + fk1 * 2 + fb;
    hmir32[(size_t)(grp * 2 + 1) * SLOTW + rem] =
        (fcol == 350) ? 0x3F800000u : 0u;
  }
  if (rem < 32) {
    tagbuf[(size_t)(grp * 2 + 0) * 32 + rem] = 0u;
    tagbuf[(size_t)(grp * 2 + 1) * 32 + rem] = 0u;
  }
  if (rem == 0) flagbuf[grp * 16] = 0u;
}

// ---- main: persistent, 2 waves/block, weights in regs, LDS-shared slab ----
__global__ __launch_bounds__(128)
__attribute__((amdgpu_waves_per_eu(1, 1)))
void lstm_kernel(const short* __restrict__ xbf, const short* __restrict__ wswz,
                 unsigned short* __restrict__ hb16, uint32_t* __restrict__ hmir32,
                 uint32_t* __restrict__ tagbuf, uint32_t* __restrict__ flagbuf,
                 const float* __restrict__ dense_w, float* __restrict__ wpart) {
  __shared__ float lds_part[2][T_][16];      // 64 KB dense-head partials
  __shared__ u64t  lds_stage[2][11][64][2];  // 22 KB shared h slab (dbuf t&1)

  const int tid  = threadIdx.x;
  const int lane = tid & 63;
  const int wv   = tid >> 6;            // 0..1
  const int l15  = lane & 15;
  const int quad = lane >> 4;
  const int grp  = blockIdx.x & 15;     // same-XCD heuristic (fast path only)
  const int j    = blockIdx.x >> 4;     // 0..10
  const int tileg = 2 * j + wv;         // this wave's col tile 0..21

  // weights -> registers ONCE
  short8 wreg[4][KC];
  #pragma unroll
  for (int g = 0; g < 4; ++g)
    #pragma unroll
    for (int kc = 0; kc < KC; ++kc)
      wreg[g][kc] = *(const short8*)(wswz +
          (((size_t)kc * NT + (g * 22 + tileg)) * 64 + lane) * 8);

  const int col = tileg * 16 + l15;               // gate-relative col 0..351
  const float dwv = (col < U_) ? dense_w[col] : 0.f;
  float cst[4] = {0.f, 0.f, 0.f, 0.f};

  // fast bf16 producer: ushort idx = pbase_us + r*8 (rows quad*4+r)
  const int pblk = col >> 5, pc32 = col & 31;
  const int pbase_us = pblk * 512 + ((pc32 >> 3) * 16 + quad * 4) * 8 + (pc32 & 7);
  // mirror (R10 tag-in-word) offset, +r*4 per row
  const int colrem = col & 31;
  const int fastoff = (((col >> 5) * 2 + ((colrem >> 2) & 1)) * 256)
                    + (((colrem >> 3) * 16 + quad * 4) * 4)
                    + (((colrem >> 1) & 1) * 2) + (col & 1);

  const short* xrow = xbf + ((size_t)(grp * NB + l15) * T_) * F_ + quad * 8;
  unsigned short* hbb = hb16 + (size_t)grp * 2 * HSLOTUS;
  uint32_t* hm  = hmir32 + (size_t)grp * 2 * SLOTW;
  uint32_t* tgg = tagbuf + (size_t)grp * 2 * 32;
  uint32_t* flagp = flagbuf + grp * 16;

  // load split: wave0 -> blocks 0..5 (tiles/tags 0..11); wave1 -> 6..10
  const int bbase = wv ? 6 : 0;
  const int nblk  = wv ? 5 : 6;
  const int tbase = wv ? 12 : 0;
  const int tcnt  = wv ? 10 : 12;
  const int tagidx = (lane < tcnt) ? (tbase + lane) : 31;  // word31: always 0

  bool mm = false;                                 // mirror (degraded) mode
  const short hs_init = (col == 350) ? (short)0x3F80 : 0;
  uint32_t wout[4], wout_prev[4];
  #pragma unroll
  for (int r = 0; r < 4; ++r)
    wout[r] = wout_prev[r] = ((uint32_t)(unsigned short)hs_init) << 16;

  // x software pipeline prologue: load t=0 (single cold stall, once)
  short8 axf = *(const short8*)(xrow);

  #pragma unroll 1
  for (int t = 0; t < T_; ++t) {
    // x prefetch for t+1 at the TOP of iter t (~one iteration of lead)
    const int tn = (t + 1 < T_) ? (t + 1) : 0;
    short8 axf_nx = *(const short8*)(xrow + tn * F_);

    // first tag probe issued BEFORE kc=0 MFMAs (latency overlap)
    const uint32_t want = (uint32_t)t;
    const uint32_t* tgr = tgg + (size_t)((t + 1) & 1) * 32;
    uint32_t tv = __hip_atomic_load(tgr + tagidx, __ATOMIC_RELAXED,
                                    __HIP_MEMORY_SCOPE_AGENT);

    // kc=0 (x-only) MFMA — h-independent; axf loaded one iteration ago
    float4_ acc[4];
    #pragma unroll
    for (int g = 0; g < 4; ++g) {
      float4_ z = (float4_){0.f, 0.f, 0.f, 0.f};
      acc[g] = __builtin_amdgcn_mfma_f32_16x16x32_bf16(axf, wreg[g][0], z, 0, 0, 0);
    }

    // ---- spin on OWN tag subset; distress -> mirror subset ----
    union { u64t q[2]; short8 s; } mfrag[6];       // mirror-mode staging
    bool gotm = false;
    bool ready = (bool)__all((int)(lane >= tcnt || tv == want));
    int tries = 0;
    while (!ready) {
      ++tries;
      if (!mm) {
        if ((tries & 63) == 0) {                    // poll distress (system)
          uint32_t f = __hip_atomic_load(flagp, __ATOMIC_RELAXED,
                                         __HIP_MEMORY_SCOPE_SYSTEM);
          if (f) mm = true;
        }
        if (tries == 16384) {                       // raise distress
          if (lane == 0)
            __hip_atomic_store(flagp, 1u, __ATOMIC_RELAXED,
                               __HIP_MEMORY_SCOPE_SYSTEM);
          mm = true;
        }
        if (mm) {
          // dump last two h vectors (self-validating tag-in-word)
          uint32_t* md1 = hm + (size_t)((t + 1) & 1) * SLOTW + fastoff; // tag t
          uint32_t* md0 = hm + (size_t)(t & 1) * SLOTW + fastoff;      // tag t-1
          #pragma unroll
          for (int r = 0; r < 4; ++r) {
            __hip_atomic_store(md1 + r * 4, wout[r], __ATOMIC_RELAXED,
                               __HIP_MEMORY_SCOPE_AGENT);
            __hip_atomic_store(md0 + r * 4, wout_prev[r], __ATOMIC_RELAXED,
                               __HIP_MEMORY_SCOPE_AGENT);
          }
        }
      } else {
        // mirror attempt: R10 tag-in-word path, OWN block subset
        const u64t* mq = (const u64t*)(hm + (size_t)((t + 1) & 1) * SLOTW)
                       + (size_t)lane * 2;
        u64t q[24];
        for (int ii = 0; ii < nblk; ++ii) {
          int i2 = bbase + ii;
          const u64t* pa = mq + (size_t)(2 * i2) * 128;
          const u64t* pb = mq + (size_t)(2 * i2 + 1) * 128;
          q[4 * ii + 0] = __hip_atomic_load(pa,     __ATOMIC_RELAXED, __HIP_MEMORY_SCOPE_AGENT);
          q[4 * ii + 1] = __hip_atomic_load(pa + 1, __ATOMIC_RELAXED, __HIP_MEMORY_SCOPE_AGENT);
          q[4 * ii + 2] = __hip_atomic_load(pb,     __ATOMIC_RELAXED, __HIP_MEMORY_SCOPE_AGENT);
          q[4 * ii + 3] = __hip_atomic_load(pb + 1, __ATOMIC_RELAXED, __HIP_MEMORY_SCOPE_AGENT);
        }
        const uint32_t tag16 = want & 0xFFFFu;
        uint32_t bad = 0;
        for (int ii = 0; ii < 4 * nblk; ++ii) {
          bad |= ((uint32_t)q[ii] ^ tag16);
          bad |= ((uint32_t)(q[ii] >> 32) ^ tag16);
        }
        if ((bool)__all((int)((bad & 0xFFFFu) == 0))) {
          for (int ii = 0; ii < nblk; ++ii) {
            #pragma unroll
            for (int k = 0; k < 4; ++k) {
              uint32_t lo = (uint32_t)q[4 * ii + k];
              uint32_t hi = (uint32_t)(q[4 * ii + k] >> 32);
              ((uint32_t*)&mfrag[ii])[k] = (lo >> 16) | (hi & 0xFFFF0000u);
            }
          }
          gotm = true;
          break;
        }
      }
      tv = __hip_atomic_load(tgr + tagidx, __ATOMIC_RELAXED,
                             __HIP_MEMORY_SCOPE_AGENT);
      ready = (bool)__all((int)(lane >= tcnt || tv == want));
    }

    // ---- stage OWN blocks into LDS ----
    if (!gotm) {
      const u64t* hq = (const u64t*)(hbb + (size_t)((t + 1) & 1) * HSLOTUS)
                     + (size_t)lane * 2;
      for (int ii = 0; ii < nblk; ++ii) {
        int b = bbase + ii;
        u64t qa = __hip_atomic_load(hq + (size_t)b * 128,     __ATOMIC_RELAXED, __HIP_MEMORY_SCOPE_AGENT);
        u64t qb = __hip_atomic_load(hq + (size_t)b * 128 + 1, __ATOMIC_RELAXED, __HIP_MEMORY_SCOPE_AGENT);
        lds_stage[t & 1][b][lane][0] = qa;
        lds_stage[t & 1][b][lane][1] = qb;
      }
    } else {
      for (int ii = 0; ii < nblk; ++ii) {
        int b = bbase + ii;
        lds_stage[t & 1][b][lane][0] = mfrag[ii].q[0];
        lds_stage[t & 1][b][lane][1] = mfrag[ii].q[1];
      }
    }
    asm volatile("s_waitcnt lgkmcnt(0)" ::: "memory");
    __builtin_amdgcn_s_barrier();
    __builtin_amdgcn_sched_barrier(0);

    // ---- MFMA over kc=1..11 from the shared LDS slab ----
    #pragma unroll
    for (int i = 0; i < 11; ++i) {
      union { u64t q[2]; short8 s; } u;
      u.q[0] = lds_stage[t & 1][i][lane][0];
      u.q[1] = lds_stage[t & 1][i][lane][1];
      #pragma unroll
      for (int g = 0; g < 4; ++g)
        acc[g] = __builtin_amdgcn_mfma_f32_16x16x32_bf16(u.s, wreg[g][i + 1], acc[g], 0, 0, 0);
    }

    // update: lane covers rows quad*4+r at its col; gates in registers
    unsigned short* hwp = hbb + (size_t)(t & 1) * HSLOTUS + pbase_us;
    const uint32_t otag = (uint32_t)(t + 1);
    float hn[4];
    #pragma unroll
    for (int r = 0; r < 4; ++r) {
      float ig = __builtin_amdgcn_rcpf(1.f + __expf(-acc[0][r]));
      float fg = __builtin_amdgcn_rcpf(1.f + __expf(-acc[1][r]));
      float gg = fmaxf(acc[2][r], 0.f);
      float og = __builtin_amdgcn_rcpf(1.f + __expf(-acc[3][r]));
      float cn = fg * cst[r] + ig * gg;
      cst[r] = cn;
      hn[r] = og * fmaxf(cn, 0.f);
      short hs = f2bf(hn[r]);
      if (col == 350) hs = (short)0x3F80;        // bias-row input stays 1.0
      else if (col == 351) hs = 0;
      wout_prev[r] = wout[r];
      wout[r] = (((uint32_t)(unsigned short)hs) << 16) | (otag & 0xFFFFu);
      hwp[r * 8] = (unsigned short)hs;           // fast bf16 data store (L2)
    }
    // publish tag with RELEASE (drains the 4 data stores first)
    if (lane == 0)
      __hip_atomic_store(tgg + (size_t)(t & 1) * 32 + tileg, otag,
                         __ATOMIC_RELEASE, __HIP_MEMORY_SCOPE_WORKGROUP);
    // degraded mode: also keep the coherent mirror current
    if (mm) {
      uint32_t* hwrm = hm + (size_t)(t & 1) * SLOTW + fastoff;
      #pragma unroll
      for (int r = 0; r < 4; ++r)
        __hip_atomic_store(hwrm + r * 4, wout[r], __ATOMIC_RELAXED,
                           __HIP_MEMORY_SCOPE_AGENT);
    }

    // dense head AFTER publish (off the recurrence; wave has slack here)
    #pragma unroll
    for (int r = 0; r < 4; ++r) {
      float s = hn[r] * dwv;
      s += __shfl_xor(s, 1); s += __shfl_xor(s, 2);
      s += __shfl_xor(s, 4); s += __shfl_xor(s, 8);
      if (l15 == 0) lds_part[wv][t][quad * 4 + r] = s;
    }

    axf = axf_nx;                                  // x pipeline shift
  }

  // bulk-store dense partials (once)
  __syncthreads();
  float* wp = wpart + ((size_t)(grp * NCB + j) * NB) * T_;
  for (int i = tid; i < NB * T_; i += 128) {
    int t = i & (T_ - 1), row = i >> 9;
    wp[(size_t)row * T_ + t] = lds_part[0][t][row] + lds_part[1][t][row];
  }
}

// ---- final: out[b,t] = db + sum_j wpart[grp][j][row][t] ----
__global__ void reduce_out(const float* __restrict__ wpart,
                           const float* __restrict__ dense_b,
                           float* __restrict__ out) {
  int i = blockIdx.x * 256 + threadIdx.x;   // i = b*T + t
  int b = i >> 9, t = i & 511;
  int grp = b >> 4, row = b & 15;
  float s = dense_b[0];
  #pragma unroll
  for (int j = 0; j < NCB; ++j)
    s += wpart[(((size_t)grp * NCB + j) * NB + row) * T_ + t];
  out[i] = s;
}

extern "C" void kernel_launch(void* const* d_in, const int* in_sizes, int n_in,
                              void* d_out, int out_size, void* d_ws, size_t ws_size,
                              hipStream_t stream) {
  const float* x    = (const float*)d_in[0];
  const float* kern = (const float*)d_in[1];
  const float* rk   = (const float*)d_in[2];
  const float* bias = (const float*)d_in[3];
  const float* dw   = (const float*)d_in[4];
  const float* db   = (const float*)d_in[5];
  float* out = (float*)d_out;

  char* ws = (char*)d_ws;
  short*          wswz   = (short*)(ws);
  short*          xbf    = (short*)(ws + OFF_XBF);
  unsigned short* hb16   = (unsigned short*)(ws + OFF_HBUF);
  uint32_t*       hmir32 = (uint32_t*)(ws + OFF_HMIR);
  uint32_t*       tagbuf = (uint32_t*)(ws + OFF_TAG);
  uint32_t*       flagbuf= (uint32_t*)(ws + OFF_FLG);
  float*          wpart  = (float*)(ws + OFF_WP);

  prep_w<<<NT, 64, 0, stream>>>(kern, rk, bias, wswz);
  prep_x<<<(256 * T_ * F_) / (256 * 4), 256, 0, stream>>>(x, xbf);
  init_all<<<(NGRP * HSLOTUS) / 256, 256, 0, stream>>>(hb16, hmir32, tagbuf, flagbuf);
  lstm_kernel<<<NGRP * NCB, 128, 0, stream>>>(xbf, wswz, hb16, hmir32, tagbuf,
                                              flagbuf, dw, wpart);
  reduce_out<<<(256 * T_) / 256, 256, 0, stream>>>(wpart, db, out);
}

// Round 10
// 947.993 us; speedup vs baseline: 1.3262x; 1.3262x over previous
//
#include <hip/hip_runtime.h>
#include <stdint.h>

// LSTM B=256,T=512,F=32,U=350; gates i,f,g(relu),o; h=o*relu(c); out=h.dw+db
//
// R18: R14 base (883us) with the x prefetch moved OFF the vmcnt queue head.
//  R15/R16 postmortem: split-K and LDS-slab-sharing both regressed — any
//  intra-block coupling (barrier/LDS round trip) adds to the period; group
//  waves are already near-synchronized. Reverted to R14 exactly.
//  Key insight (m135): gfx9 loads RETIRE IN ISSUE ORDER. R14 issues the
//  x(t+1) load (HBM stream, ~900cy; FETCH==xbf size, never re-read) at the
//  loop TOP, BEFORE the 22 critical h-slab loads: every s_waitcnt for the
//  h loads transitively waits the older x load -> ~900cy retirement
//  barrier in front of EVERY step's h data. (Explains R14's tiny -2%:
//  only the spin overlap was gained. R13's bottom placement was right but
//  confounded by its dense-head regression.)
//  R18 change (only one): issue x(t+1) right AFTER the tag publish —
//  ~1.3kcy of lead (dense head + next spin + kc0) before its retirement
//  is needed; next step's h loads become the oldest outstanding. The
//  prefetch uses relaxed-agent u64 atomic loads (same proven form as the
//  h loads) so the compiler cannot hoist it back across the spin/publish.
//  Everything else byte-identical R14: bf16 A-frag fast slab (11KB, no
//  repack), 22-word tag array w/ RELEASE-workgroup publish, dense head
//  after publish, distress->mirror degraded mode, depth-2 ping-pong.

#define T_   512
#define F_   32
#define U_   350
#define G4   1400
#define NGRP 16
#define NB   16
#define NCB  11
#define KC   12
#define NT   88
#define HSLOTUS 5632    // ushorts per bf16 fast slot (11 blk * 512)
#define SLOTW   5632    // u32 words per mirror slot (R10 layout)

typedef __attribute__((ext_vector_type(8))) short  short8;
typedef __attribute__((ext_vector_type(4))) short  short4_;
typedef __attribute__((ext_vector_type(4))) float  float4_;
typedef unsigned long long u64t;

__device__ __forceinline__ short f2bf(float f) {
  union { float f; uint32_t u; } v; v.f = f;
  return (short)((v.u + 0x7FFFu + ((v.u >> 16) & 1u)) >> 16);
}

// ---- workspace layout (bytes) ----
#define SZ_W     (NT*KC*64*8*2u)                        // 1,081,344
#define OFF_XBF  (SZ_W)
#define SZ_XBF   (256u*T_*F_*2u)                        // 8,388,608
#define OFF_HBUF (OFF_XBF + SZ_XBF)
#define SZ_HBUF  (NGRP*2u*HSLOTUS*2u)                   // 360,448
#define OFF_HMIR (OFF_HBUF + SZ_HBUF)
#define SZ_HMIR  (NGRP*2u*SLOTW*4u)                     // 720,896
#define OFF_TAG  (OFF_HMIR + SZ_HMIR)
#define SZ_TAG   (NGRP*2u*32u*4u)                       // 4,096
#define OFF_FLG  (OFF_TAG + SZ_TAG)
#define SZ_FLG   (NGRP*16u*4u)                          // 1,024
#define OFF_WP   (OFF_FLG + SZ_FLG)
#define SZ_WP    (NGRP*NCB*NB*T_*4u)                    // 5,767,168

// ---- prep: W_swz[kc][tile][lane][8] bf16 in MFMA B-fragment order ----
__global__ void prep_w(const float* __restrict__ kern,
                       const float* __restrict__ rk,
                       const float* __restrict__ bias,
                       short* __restrict__ wswz) {
  const int tile = blockIdx.x, lane = threadIdx.x;
  const int g = tile / 22, jt = tile % 22;
  const int colg = jt * 16 + (lane & 15);
  const int src = g * U_ + colg;
  const bool valid = (colg < U_);
  const int kbase = (lane >> 4) * 8;
  for (int kc = 0; kc < KC; ++kc) {
    short8 pack;
    #pragma unroll
    for (int jj = 0; jj < 8; ++jj) {
      int k = kc * 32 + kbase + jj;
      float v = 0.f;
      if (valid) {
        if (k < F_)            v = kern[k * G4 + src];
        else if (k < F_ + U_)  v = rk[(k - F_) * G4 + src];
        else if (k == F_ + U_) v = bias[src];
      }
      pack[jj] = f2bf(v);
    }
    *(short8*)(wswz + (((size_t)kc * NT + tile) * 64 + lane) * 8) = pack;
  }
}

// ---- prep: x f32 -> bf16 ([b][t][f], contiguous 16B A-frag loads) ----
__global__ void prep_x(const float* __restrict__ x, short* __restrict__ xbf) {
  int i = (blockIdx.x * 256 + threadIdx.x) * 4;
  float4_ v = *(const float4_*)(x + i);
  short4_ o;
  #pragma unroll
  for (int jj = 0; jj < 4; ++jj) o[jj] = f2bf(v[jj]);
  *(short4_*)(xbf + i) = o;
}

// ---- init: slot1 = h_{-1}=0 tag 0 (bias col 350 = 1.0); tags; flag ----
// Fast slot0 / mirror slot0 need no init (reads are tag-gated / tag-in-word
// poison-safe). Tag slot0 init 0 is safe: slot0 wants odd tags only.
__global__ void init_all(unsigned short* __restrict__ hb16,
                         uint32_t* __restrict__ hmir32,
                         uint32_t* __restrict__ tagbuf,
                         uint32_t* __restrict__ flagbuf) {
  int i = blockIdx.x * 256 + threadIdx.x;            // 0 .. NGRP*5632-1
  int grp = i / HSLOTUS, rem = i % HSLOTUS;
  // fast bf16 slot1: rem = blk*512 + (quad_c*16+row)*8 + cpos
  {
    int blk = rem >> 9, quadc = (rem >> 7) & 3, cpos = rem & 7;
    int col = blk * 32 + quadc * 8 + cpos;
    hb16[(size_t)(grp * 2 + 1) * HSLOTUS + rem] =
        (col == 350) ? (unsigned short)0x3F80 : 0;
  }
  // mirror slot1 (R10 tag-in-word layout)
  {
    int blkm = rem >> 8, off = rem & 255;
    int fi = blkm >> 1, fk2 = blkm & 1, fquadc = off >> 6;
    int fk1 = (off >> 1) & 1, fb = off & 1;
    int fcol = fi * 32 + fquadc * 8 + fk2 * 4 + fk1 * 2 + fb;
    hmir32[(size_t)(grp * 2 + 1) * SLOTW + rem] =
        (fcol == 350) ? 0x3F800000u : 0u;
  }
  if (rem < 32) {
    tagbuf[(size_t)(grp * 2 + 0) * 32 + rem] = 0u;
    tagbuf[(size_t)(grp * 2 + 1) * 32 + rem] = 0u;
  }
  if (rem == 0) flagbuf[grp * 16] = 0u;
}

// ---- main: persistent, 2 decoupled waves per block, weights in regs ----
__global__ __launch_bounds__(128)
__attribute__((amdgpu_waves_per_eu(1, 1)))
void lstm_kernel(const short* __restrict__ xbf, const short* __restrict__ wswz,
                 unsigned short* __restrict__ hb16, uint32_t* __restrict__ hmir32,
                 uint32_t* __restrict__ tagbuf, uint32_t* __restrict__ flagbuf,
                 const float* __restrict__ dense_w, float* __restrict__ wpart) {
  __shared__ float lds_part[2][T_][16];   // 64 KB dense-head partials

  const int tid  = threadIdx.x;
  const int lane = tid & 63;
  const int wv   = tid >> 6;            // 0..1
  const int l15  = lane & 15;
  const int quad = lane >> 4;
  const int grp  = blockIdx.x & 15;     // same-XCD heuristic (fast path only)
  const int j    = blockIdx.x >> 4;     // 0..10
  const int tileg = 2 * j + wv;         // this wave's col tile 0..21

  // weights -> registers ONCE
  short8 wreg[4][KC];
  #pragma unroll
  for (int g = 0; g < 4; ++g)
    #pragma unroll
    for (int kc = 0; kc < KC; ++kc)
      wreg[g][kc] = *(const short8*)(wswz +
          (((size_t)kc * NT + (g * 22 + tileg)) * 64 + lane) * 8);

  const int col = tileg * 16 + l15;               // gate-relative col 0..351
  const float dwv = (col < U_) ? dense_w[col] : 0.f;
  float cst[4] = {0.f, 0.f, 0.f, 0.f};

  // fast bf16 producer: ushort idx = pbase_us + r*8 (rows quad*4+r)
  const int pblk = col >> 5, pc32 = col & 31;
  const int pbase_us = pblk * 512 + ((pc32 >> 3) * 16 + quad * 4) * 8 + (pc32 & 7);
  // mirror (R10 tag-in-word) offset, +r*4 per row
  const int colrem = col & 31;
  const int fastoff = (((col >> 5) * 2 + ((colrem >> 2) & 1)) * 256)
                    + (((colrem >> 3) * 16 + quad * 4) * 4)
                    + (((colrem >> 1) & 1) * 2) + (col & 1);

  const short* xrow = xbf + ((size_t)(grp * NB + l15) * T_) * F_ + quad * 8;
  unsigned short* hbb = hb16 + (size_t)grp * 2 * HSLOTUS;
  uint32_t* hm  = hmir32 + (size_t)grp * 2 * SLOTW;
  uint32_t* tgg = tagbuf + (size_t)grp * 2 * 32;
  uint32_t* flagp = flagbuf + grp * 16;
  const int tagidx = (lane < 22) ? lane : 31;     // word31: always 0

  bool mm = false;                                 // mirror (degraded) mode
  const short hs_init = (col == 350) ? (short)0x3F80 : 0;
  uint32_t wout[4], wout_prev[4];
  #pragma unroll
  for (int r = 0; r < 4; ++r)
    wout[r] = wout_prev[r] = ((uint32_t)(unsigned short)hs_init) << 16;

  // x software pipeline prologue: load t=0 (single cold stall, once)
  short8 axf = *(const short8*)(xrow);

  #pragma unroll 1
  for (int t = 0; t < T_; ++t) {
    // first tag probe issued BEFORE kc=0 MFMAs (latency overlap)
    const uint32_t want = (uint32_t)t;
    const uint32_t* tgr = tgg + (size_t)((t + 1) & 1) * 32;
    uint32_t tv = __hip_atomic_load(tgr + tagidx, __ATOMIC_RELAXED,
                                    __HIP_MEMORY_SCOPE_AGENT);

    // kc=0 (x-only) MFMA — h-independent; axf loaded LAST iteration,
    // post-publish: its HBM latency fully drained off the vmcnt queue.
    float4_ acc[4];
    #pragma unroll
    for (int g = 0; g < 4; ++g) {
      float4_ z = (float4_){0.f, 0.f, 0.f, 0.f};
      acc[g] = __builtin_amdgcn_mfma_f32_16x16x32_bf16(axf, wreg[g][0], z, 0, 0, 0);
    }

    short8 afr[11];
    bool ready = (bool)__all((int)(lane >= 22 || tv == want));
    bool gotm = false;
    int tries = 0;
    while (!ready) {
      ++tries;
      if (!mm) {
        if ((tries & 63) == 0) {                    // poll distress (system)
          uint32_t f = __hip_atomic_load(flagp, __ATOMIC_RELAXED,
                                         __HIP_MEMORY_SCOPE_SYSTEM);
          if (f) mm = true;
        }
        if (tries == 16384) {                       // raise distress
          if (lane == 0)
            __hip_atomic_store(flagp, 1u, __ATOMIC_RELAXED,
                               __HIP_MEMORY_SCOPE_SYSTEM);
          mm = true;
        }
        if (mm) {
          // dump last two h vectors (self-validating tag-in-word)
          uint32_t* md1 = hm + (size_t)((t + 1) & 1) * SLOTW + fastoff; // tag t
          uint32_t* md0 = hm + (size_t)(t & 1) * SLOTW + fastoff;      // tag t-1
          #pragma unroll
          for (int r = 0; r < 4; ++r) {
            __hip_atomic_store(md1 + r * 4, wout[r], __ATOMIC_RELAXED,
                               __HIP_MEMORY_SCOPE_AGENT);
            __hip_atomic_store(md0 + r * 4, wout_prev[r], __ATOMIC_RELAXED,
                               __HIP_MEMORY_SCOPE_AGENT);
          }
        }
      } else {
        // mirror attempt: R10's coalesced tag-in-word path
        const u64t* mq = (const u64t*)(hm + (size_t)((t + 1) & 1) * SLOTW)
                       + (size_t)lane * 2;
        u64t q[44];
        #pragma unroll
        for (int i = 0; i < 11; ++i) {
          const u64t* pa = mq + (size_t)(2 * i) * 128;
          const u64t* pb = mq + (size_t)(2 * i + 1) * 128;
          q[4 * i + 0] = __hip_atomic_load(pa,     __ATOMIC_RELAXED, __HIP_MEMORY_SCOPE_AGENT);
          q[4 * i + 1] = __hip_atomic_load(pa + 1, __ATOMIC_RELAXED, __HIP_MEMORY_SCOPE_AGENT);
          q[4 * i + 2] = __hip_atomic_load(pb,     __ATOMIC_RELAXED, __HIP_MEMORY_SCOPE_AGENT);
          q[4 * i + 3] = __hip_atomic_load(pb + 1, __ATOMIC_RELAXED, __HIP_MEMORY_SCOPE_AGENT);
        }
        const uint32_t tag16 = want & 0xFFFFu;
        uint32_t bad = 0;
        #pragma unroll
        for (int i = 0; i < 44; ++i) {
          bad |= ((uint32_t)q[i] ^ tag16);
          bad |= ((uint32_t)(q[i] >> 32) ^ tag16);
        }
        if ((bool)__all((int)((bad & 0xFFFFu) == 0))) {
          #pragma unroll
          for (int i = 0; i < 11; ++i) {
            union { uint32_t w[4]; short8 s; } u;
            #pragma unroll
            for (int k = 0; k < 4; ++k) {
              uint32_t lo = (uint32_t)q[4 * i + k];
              uint32_t hi = (uint32_t)(q[4 * i + k] >> 32);
              u.w[k] = (lo >> 16) | (hi & 0xFFFF0000u);
            }
            afr[i] = u.s;
          }
          gotm = true;
          break;
        }
      }
      tv = __hip_atomic_load(tgr + tagidx, __ATOMIC_RELAXED,
                             __HIP_MEMORY_SCOPE_AGENT);
      ready = (bool)__all((int)(lane >= 22 || tv == want));
    }

    if (!gotm) {
      // coalesced bf16 A-frag load: lane L reads 16B at blk*1024 + L*16
      const u64t* hq = (const u64t*)(hbb + (size_t)((t + 1) & 1) * HSLOTUS)
                     + (size_t)lane * 2;
      #pragma unroll
      for (int i = 0; i < 11; ++i) {
        union { u64t q[2]; short8 s; } u;
        u.q[0] = __hip_atomic_load(hq + (size_t)i * 128,     __ATOMIC_RELAXED, __HIP_MEMORY_SCOPE_AGENT);
        u.q[1] = __hip_atomic_load(hq + (size_t)i * 128 + 1, __ATOMIC_RELAXED, __HIP_MEMORY_SCOPE_AGENT);
        afr[i] = u.s;
      }
    }

    // MFMA over kc=1..11 (no repack needed)
    #pragma unroll
    for (int i = 0; i < 11; ++i)
      #pragma unroll
      for (int g = 0; g < 4; ++g)
        acc[g] = __builtin_amdgcn_mfma_f32_16x16x32_bf16(afr[i], wreg[g][i + 1], acc[g], 0, 0, 0);

    // update: lane covers rows quad*4+r at its col; gates in registers
    unsigned short* hwp = hbb + (size_t)(t & 1) * HSLOTUS + pbase_us;
    const uint32_t otag = (uint32_t)(t + 1);
    float hn[4];
    #pragma unroll
    for (int r = 0; r < 4; ++r) {
      float ig = __builtin_amdgcn_rcpf(1.f + __expf(-acc[0][r]));
      float fg = __builtin_amdgcn_rcpf(1.f + __expf(-acc[1][r]));
      float gg = fmaxf(acc[2][r], 0.f);
      float og = __builtin_amdgcn_rcpf(1.f + __expf(-acc[3][r]));
      float cn = fg * cst[r] + ig * gg;
      cst[r] = cn;
      hn[r] = og * fmaxf(cn, 0.f);
      short hs = f2bf(hn[r]);
      if (col == 350) hs = (short)0x3F80;        // bias-row input stays 1.0
      else if (col == 351) hs = 0;
      wout_prev[r] = wout[r];
      wout[r] = (((uint32_t)(unsigned short)hs) << 16) | (otag & 0xFFFFu);
      hwp[r * 8] = (unsigned short)hs;           // fast bf16 data store (L2)
    }
    // publish tag with RELEASE (drains the 4 data stores first)
    if (lane == 0)
      __hip_atomic_store(tgg + (size_t)(t & 1) * 32 + tileg, otag,
                         __ATOMIC_RELEASE, __HIP_MEMORY_SCOPE_WORKGROUP);

    // x prefetch for t+1 issued POST-publish: ~1.3kcy of lead; retires off
    // the critical path, so next step's h-loads are the oldest outstanding
    // vmcnt entries. Atomic form pins placement (no hoist across the spin).
    short8 axf_nx;
    {
      const int tn = (t + 1 < T_) ? (t + 1) : 0;
      const u64t* xq = (const u64t*)(xrow + tn * F_);
      union { u64t q[2]; short8 s; } ux;
      ux.q[0] = __hip_atomic_load(xq,     __ATOMIC_RELAXED, __HIP_MEMORY_SCOPE_AGENT);
      ux.q[1] = __hip_atomic_load(xq + 1, __ATOMIC_RELAXED, __HIP_MEMORY_SCOPE_AGENT);
      axf_nx = ux.s;
    }

    // degraded mode: also keep the coherent mirror current
    if (mm) {
      uint32_t* hwrm = hm + (size_t)(t & 1) * SLOTW + fastoff;
      #pragma unroll
      for (int r = 0; r < 4; ++r)
        __hip_atomic_store(hwrm + r * 4, wout[r], __ATOMIC_RELAXED,
                           __HIP_MEMORY_SCOPE_AGENT);
    }

    // dense head AFTER publish (off the recurrence; wave has slack here)
    #pragma unroll
    for (int r = 0; r < 4; ++r) {
      float s = hn[r] * dwv;
      s += __shfl_xor(s, 1); s += __shfl_xor(s, 2);
      s += __shfl_xor(s, 4); s += __shfl_xor(s, 8);
      if (l15 == 0) lds_part[wv][t][quad * 4 + r] = s;
    }

    axf = axf_nx;                                  // pipeline shift
  }

  // bulk-store dense partials (once)
  __syncthreads();
  float* wp = wpart + ((size_t)(grp * NCB + j) * NB) * T_;
  for (int i = tid; i < NB * T_; i += 128) {
    int t = i & (T_ - 1), row = i >> 9;
    wp[(size_t)row * T_ + t] = lds_part[0][t][row] + lds_part[1][t][row];
  }
}

// ---- final: out[b,t] = db + sum_j wpart[grp][j][row][t] ----
__global__ void reduce_out(const float* __restrict__ wpart,
                           const float* __restrict__ dense_b,
                           float* __restrict__ out) {
  int i = blockIdx.x * 256 + threadIdx.x;   // i = b*T + t
  int b = i >> 9, t = i & 511;
  int grp = b >> 4, row = b & 15;
  float s = dense_b[0];
  #pragma unroll
  for (int j = 0; j < NCB; ++j)
    s += wpart[(((size_t)grp * NCB + j) * NB + row) * T_ + t];
  out[i] = s;
}

extern "C" void kernel_launch(void* const* d_in, const int* in_sizes, int n_in,
                              void* d_out, int out_size, void* d_ws, size_t ws_size,
                              hipStream_t stream) {
  const float* x    = (const float*)d_in[0];
  const float* kern = (const float*)d_in[1];
  const float* rk   = (const float*)d_in[2];
  const float* bias = (const float*)d_in[3];
  const float* dw   = (const float*)d_in[4];
  const float* db   = (const float*)d_in[5];
  float* out = (float*)d_out;

  char* ws = (char*)d_ws;
  short*          wswz   = (short*)(ws);
  short*          xbf    = (short*)(ws + OFF_XBF);
  unsigned short* hb16   = (unsigned short*)(ws + OFF_HBUF);
  uint32_t*       hmir32 = (uint32_t*)(ws + OFF_HMIR);
  uint32_t*       tagbuf = (uint32_t*)(ws + OFF_TAG);
  uint32_t*       flagbuf= (uint32_t*)(ws + OFF_FLG);
  float*          wpart  = (float*)(ws + OFF_WP);

  prep_w<<<NT, 64, 0, stream>>>(kern, rk, bias, wswz);
  prep_x<<<(256 * T_ * F_) / (256 * 4), 256, 0, stream>>>(x, xbf);
  init_all<<<(NGRP * HSLOTUS) / 256, 256, 0, stream>>>(hb16, hmir32, tagbuf, flagbuf);
  lstm_kernel<<<NGRP * NCB, 128, 0, stream>>>(xbf, wswz, hb16, hmir32, tagbuf,
                                              flagbuf, dw, wpart);
  reduce_out<<<(256 * T_) / 256, 256, 0, stream>>>(wpart, db, out);
}